// Round 5
// baseline (7840.459 us; speedup 1.0000x reference)
//
#include <hip/hip_runtime.h>
#include <math.h>

#define EMB   256
#define TWOE  512
#define NINIT 1024
#define NSTEP 512
#define NPS   256
#define TOTAL (NINIT + NSTEP * NPS)   // 132096
#define MM    65536

// ---- workspace layout (bytes) ----
#define OFF_VEC 0
#define OFF_H   (TOTAL * EMB * 4)                  // 135266304
#define OFF_VAL (OFF_H + 2 * NPS * EMB * 4)        // hbuf double-buffered
#define OFF_CNT (OFF_VAL + MM * 4)
#define OFF_FLG (OFF_CNT + 8192)                   // 512*16 u32 flags (32KB)
#define OFF_ACC (OFF_FLG + 32768)
#define OFF_PW  (OFF_ACC + 64)

// cnt u32 layout: gc[g]=32*g (barrier arrivals), gep[g]=512+32*g (epoch),
//                 pc[g]=1024+32*g (publish arrivals, wave-granular)
// acc layout: [0]=sum(pos) [1]=sum(neg) [2]=loss [3]=posOK [4]=negOK

// ---- coherence-point (bypass L1/L2) ops ----
__device__ __forceinline__ void store_dev_f32(float* p, float v) {
  asm volatile("global_store_dword %0, %1, off sc0 sc1" :: "v"(p), "v"(v) : "memory");
}
__device__ __forceinline__ void store_dev_u32(unsigned* p, unsigned v) {
  asm volatile("global_store_dword %0, %1, off sc0 sc1" :: "v"(p), "v"(v) : "memory");
}
__device__ __forceinline__ unsigned load_dev_u32(const unsigned* p) {
  unsigned r;
  asm volatile("global_load_dword %0, %1, off sc0 sc1\n\ts_waitcnt vmcnt(0)"
               : "=v"(r) : "v"(p) : "memory");
  return r;
}
__device__ __forceinline__ float4 load_dev_f128(const float4* p) {
  float4 r;
  asm volatile("global_load_dwordx4 %0, %1, off sc0 sc1" : "=v"(r) : "v"(p));
  return r;
}

// zeros cnt(8KB) + flags(32KB) + acc + pw
__global__ void zero_scratch(unsigned* base) {
  int i = blockIdx.x * 256 + threadIdx.x;
  if (i < 10260) base[i] = 0u;
}

__global__ void init_copy(const float* __restrict__ src, float* __restrict__ dst) {
  int i = blockIdx.x * blockDim.x + threadIdx.x;
  reinterpret_cast<float4*>(dst)[i] = reinterpret_cast<const float4*>(src)[i];
}

// Persistent scan: 256 blocks x 256 threads; block (bi,bj) owns 16x16 out tile.
// Flags pre-checked one step ahead; parent gather overlapped with h exchange.
__global__ __launch_bounds__(256, 1)
void scan_kernel(const float* __restrict__ W1, const float* __restrict__ b1,
                 const float* __restrict__ W2, const float* __restrict__ b2,
                 const int* __restrict__ inds, const int* __restrict__ pars,
                 const int* __restrict__ rules,
                 float* __restrict__ vec, float* __restrict__ hbuf,
                 unsigned* __restrict__ cnt, unsigned* __restrict__ flags)
{
  __shared__ float pA[16][516];      // gathered parents (concat 2x256)
  __shared__ float wT[16][516];      // W tile transposed
  __shared__ float hL[16][260];      // h rows for phase 2
  __shared__ int spars[2][32];
  __shared__ unsigned unset_mask;    // lanes (0..31) with unconfirmed flag
  const int tid = threadIdx.x;
  const int bi = blockIdx.x >> 4;
  const int bj = blockIdx.x & 15;
  const int ti = tid >> 4;
  const int tj = tid & 15;
  const int c0 = bj * 16;
  unsigned* gc  = cnt + 32 * bi;
  unsigned* gep = cnt + 512 + 32 * bi;
  unsigned* pc  = cnt + 1024 + 32 * bi;

  // ---- prologue: stage W1(0), spars(0), gather step-0 parents (all <NINIT) ----
  {
    const float* __restrict__ W1r = W1 + (size_t)rules[0] * TWOE * EMB;
    for (int idx = tid; idx < TWOE * 4; idx += 256) {
      int k = idx >> 2, cq = idx & 3;
      float4 w = *reinterpret_cast<const float4*>(W1r + (size_t)k * EMB + c0 + cq * 4);
      wT[cq * 4 + 0][k] = w.x; wT[cq * 4 + 1][k] = w.y;
      wT[cq * 4 + 2][k] = w.z; wT[cq * 4 + 3][k] = w.w;
    }
  }
  if (tid < 32) spars[0][tid] = pars[(size_t)bi * 32 + tid];
  if (tid == 0) unset_mask = 0u;
  __syncthreads();
  for (int idx = tid; idx < 16 * 128; idx += 256) {
    int row = idx >> 7, c4 = idx & 127;
    int par = spars[0][row * 2 + (c4 >> 6)];
    float4 v = reinterpret_cast<const float4*>(vec + (size_t)par * EMB)[c4 & 63];
    reinterpret_cast<float4*>(&pA[row][0])[c4] = v;
  }
  __syncthreads();

  for (int s = 0;;) {
    const int r = rules[s];
    // ---- phase 1: h tile -> hbuf[s&1] (coherent store) ----
    {
      const float4* p4 = reinterpret_cast<const float4*>(&pA[ti][0]);
      const float4* w4 = reinterpret_cast<const float4*>(&wT[tj][0]);
      float sx = 0.f, sy = 0.f, sz = 0.f, sw = 0.f;
      #pragma unroll 8
      for (int k4 = 0; k4 < TWOE / 4; ++k4) {
        float4 a = p4[k4], w = w4[k4];
        sx += a.x * w.x; sy += a.y * w.y; sz += a.z * w.z; sw += a.w * w.w;
      }
      float h = b1[r * EMB + c0 + tj] + ((sx + sy) + (sz + sw));
      store_dev_f32(hbuf + (size_t)((s & 1) * NPS + bi * 16 + ti) * EMB + c0 + tj,
                    fmaxf(h, 0.f));
    }
    __syncthreads();   // pA & wT free
    // ---- wave0: precheck flags for s+1; waves 1-3: stage W2 ----
    if (tid < 32) {
      if (s + 1 < NSTEP) {
        int p = pars[(size_t)(s + 1) * 512 + bi * 32 + tid];
        spars[(s + 1) & 1][tid] = p;
        unsigned un = 0u;
        if (p >= NINIT) {
          int pr = p - NINIT;
          if (load_dev_u32(flags + (pr >> 8) * 16 + ((pr & 255) >> 4)) == 0u) un = 1u;
        }
        unsigned long long m = __ballot(un != 0u);
        if (tid == 0) unset_mask = (unsigned)m;
      } else if (tid == 0) {
        unset_mask = 0u;
      }
    }
    if (tid >= 64) {
      const float* __restrict__ W2r = W2 + (size_t)r * EMB * EMB;
      for (int idx = tid - 64; idx < EMB * 4; idx += 192) {
        int k = idx >> 2, cq = idx & 3;
        float4 w = *reinterpret_cast<const float4*>(W2r + (size_t)k * EMB + c0 + cq * 4);
        wT[cq * 4 + 0][k] = w.x; wT[cq * 4 + 1][k] = w.y;
        wT[cq * 4 + 2][k] = w.z; wT[cq * 4 + 3][k] = w.w;
      }
    }
    // ---- group barrier (epoch broadcast), per-wave store drain first ----
    asm volatile("s_waitcnt vmcnt(0)" ::: "memory");
    __syncthreads();
    if (tid == 0) {
      unsigned old = __hip_atomic_fetch_add(gc, 1u, __ATOMIC_RELAXED,
                                            __HIP_MEMORY_SCOPE_AGENT);
      unsigned tgt = old / 16u + 1u;
      if ((old & 15u) == 15u) store_dev_u32(gep, tgt);
      else while (load_dev_u32(gep) < tgt) __builtin_amdgcn_s_sleep(1);
    }
    __syncthreads();
    // ---- early gather for s+1 (confirmed rows) overlapped with h loads ----
    const unsigned um = unset_mask;
    if (s + 1 < NSTEP) {
      const int nslot = (s + 1) & 1;
      for (int idx = tid; idx < 16 * 128; idx += 256) {
        int row = idx >> 7, c4 = idx & 127;
        if (!((um >> (2 * row)) & 3u)) {
          int par = spars[nslot][row * 2 + (c4 >> 6)];
          float4 v = reinterpret_cast<const float4*>(vec + (size_t)par * EMB)[c4 & 63];
          reinterpret_cast<float4*>(&pA[row][0])[c4] = v;
        }
      }
    }
    // ---- coherent h loads -> hL ----
    {
      const int i0 = tid, i1 = tid + 256, i2 = tid + 512, i3 = tid + 768;
      const float4* hb = reinterpret_cast<const float4*>(
          hbuf + (size_t)((s & 1) * NPS + bi * 16) * EMB);
      float4 h0 = load_dev_f128(hb + i0);
      float4 h1 = load_dev_f128(hb + i1);
      float4 h2 = load_dev_f128(hb + i2);
      float4 h3 = load_dev_f128(hb + i3);
      asm volatile("s_waitcnt vmcnt(0)" ::: "memory");
      __builtin_amdgcn_sched_barrier(0);
      reinterpret_cast<float4*>(&hL[i0 >> 6][0])[i0 & 63] = h0;
      reinterpret_cast<float4*>(&hL[i1 >> 6][0])[i1 & 63] = h1;
      reinterpret_cast<float4*>(&hL[i2 >> 6][0])[i2 & 63] = h2;
      reinterpret_cast<float4*>(&hL[i3 >> 6][0])[i3 & 63] = h3;
    }
    __syncthreads();
    // ---- phase 2: out tile -> vec (coherent scatter) ----
    {
      const float4* p4 = reinterpret_cast<const float4*>(&hL[ti][0]);
      const float4* w4 = reinterpret_cast<const float4*>(&wT[tj][0]);
      float sx = 0.f, sy = 0.f, sz = 0.f, sw = 0.f;
      #pragma unroll 8
      for (int k4 = 0; k4 < EMB / 4; ++k4) {
        float4 a = p4[k4], w = w4[k4];
        sx += a.x * w.x; sy += a.y * w.y; sz += a.z * w.z; sw += a.w * w.w;
      }
      float o = b2[r * EMB + c0 + tj] + ((sx + sy) + (sz + sw));
      int orow = inds[s * NPS + bi * 16 + ti];
      store_dev_f32(vec + (size_t)orow * EMB + c0 + tj, o);
    }
    // ---- wave-granular publish: 64th arrival sets flag[s][bi] ----
    asm volatile("s_waitcnt vmcnt(0)" ::: "memory");
    if ((tid & 63) == 0) {
      unsigned old = __hip_atomic_fetch_add(pc, 1u, __ATOMIC_RELAXED,
                                            __HIP_MEMORY_SCOPE_AGENT);
      if ((old & 63u) == 63u) store_dev_u32(flags + s * 16 + bi, 1u);
    }
    ++s;
    if (s == NSTEP) break;
    __syncthreads();   // all threads past phase2 (wT/pA safe); um stable
    if (um != 0u) {
      // recheck the rare unconfirmed flags, then late-gather those rows
      if (tid < 32 && ((um >> tid) & 1u)) {
        int pr = spars[s & 1][tid] - NINIT;
        const unsigned* f = flags + (pr >> 8) * 16 + ((pr & 255) >> 4);
        while (load_dev_u32(f) == 0u) __builtin_amdgcn_s_sleep(1);
      }
      __syncthreads();
      const int nslot = s & 1;
      for (int idx = tid; idx < 16 * 128; idx += 256) {
        int row = idx >> 7, c4 = idx & 127;
        if ((um >> (2 * row)) & 3u) {
          int par = spars[nslot][row * 2 + (c4 >> 6)];
          float4 v = reinterpret_cast<const float4*>(vec + (size_t)par * EMB)[c4 & 63];
          reinterpret_cast<float4*>(&pA[row][0])[c4] = v;
        }
      }
    }
    // ---- stage W1 for step s ----
    {
      const float* __restrict__ W1n = W1 + (size_t)rules[s] * TWOE * EMB;
      for (int idx = tid; idx < TWOE * 4; idx += 256) {
        int k = idx >> 2, cq = idx & 3;
        float4 w = *reinterpret_cast<const float4*>(W1n + (size_t)k * EMB + c0 + cq * 4);
        wT[cq * 4 + 0][k] = w.x; wT[cq * 4 + 1][k] = w.y;
        wT[cq * 4 + 2][k] = w.z; wT[cq * 4 + 3][k] = w.w;
      }
    }
    __syncthreads();   // pA & wT ready for phase 1
  }
}

__global__ void reduce_pn(const float* __restrict__ pos, const float* __restrict__ neg,
                          double* acc) {
  double sp = 0.0, sn = 0.0;
  for (int m = blockIdx.x * blockDim.x + threadIdx.x; m < MM; m += gridDim.x * blockDim.x) {
    sp += (double)pos[m]; sn += (double)neg[m];
  }
  for (int o = 32; o; o >>= 1) { sp += __shfl_down(sp, o); sn += __shfl_down(sn, o); }
  __shared__ double rp[4], rn[4];
  int wid = threadIdx.x >> 6, lane = threadIdx.x & 63;
  if (lane == 0) { rp[wid] = sp; rn[wid] = sn; }
  __syncthreads();
  if (threadIdx.x == 0) {
    double tp = 0.0, tn = 0.0;
    for (int w = 0; w < 4; ++w) { tp += rp[w]; tn += rn[w]; }
    atomicAdd(&acc[0], tp); atomicAdd(&acc[1], tn);
  }
}

__global__ void pw_kernel(const double* __restrict__ acc, float* __restrict__ pw) {
  pw[0] = (float)(acc[1] / fmax(acc[0], 1.0));
}

__global__ __launch_bounds__(256)
void eval_kernel(const float* __restrict__ vec, const int* __restrict__ mask,
                 const float* __restrict__ eW1, const float* __restrict__ eb1,
                 const float* __restrict__ eW2, const float* __restrict__ eb2,
                 float* __restrict__ val)
{
  __shared__ float xL[64][36];
  __shared__ float wL[32][260];
  __shared__ int mrow[64];
  const int tid = threadIdx.x;
  const int a = tid >> 4, b = tid & 15;
  const int m0 = blockIdx.x * 64;
  if (tid < 64) mrow[tid] = mask[m0 + tid];
  __syncthreads();

  float acc[4][16];
  #pragma unroll
  for (int i = 0; i < 4; ++i)
    #pragma unroll
    for (int j = 0; j < 16; ++j) acc[i][j] = 0.f;

  for (int c = 0; c < 8; ++c) {
    const int e0 = c * 32;
    for (int idx = tid; idx < 64 * 8; idx += 256) {
      int rr = idx >> 3, e4 = idx & 7;
      float4 v = reinterpret_cast<const float4*>(vec + (size_t)mrow[rr] * EMB + e0)[e4];
      reinterpret_cast<float4*>(&xL[rr][0])[e4] = v;
    }
    for (int idx = tid; idx < 32 * 64; idx += 256) {
      int e = idx >> 6, k4 = idx & 63;
      reinterpret_cast<float4*>(&wL[e][0])[k4] =
          reinterpret_cast<const float4*>(eW1 + (size_t)(e0 + e) * EMB)[k4];
    }
    __syncthreads();
    #pragma unroll 4
    for (int e = 0; e < 32; ++e) {
      float xs[4];
      #pragma unroll
      for (int rr = 0; rr < 4; ++rr) xs[rr] = xL[a * 4 + rr][e];
      const float4* wr = reinterpret_cast<const float4*>(&wL[e][0]) + b * 4;
      float wk[16];
      *reinterpret_cast<float4*>(&wk[0])  = wr[0];
      *reinterpret_cast<float4*>(&wk[4])  = wr[1];
      *reinterpret_cast<float4*>(&wk[8])  = wr[2];
      *reinterpret_cast<float4*>(&wk[12]) = wr[3];
      #pragma unroll
      for (int rr = 0; rr < 4; ++rr)
        #pragma unroll
        for (int kk = 0; kk < 16; ++kk)
          acc[rr][kk] = fmaf(xs[rr], wk[kk], acc[rr][kk]);
    }
    __syncthreads();
  }

  float eb2v = eb2[0];
  float pv[4];
  #pragma unroll
  for (int rr = 0; rr < 4; ++rr) {
    float s = 0.f;
    #pragma unroll
    for (int kk = 0; kk < 16; ++kk) {
      float h = acc[rr][kk] + eb1[b * 16 + kk];
      h = fmaxf(h, 0.f);
      s += h * eW2[b * 16 + kk];
    }
    pv[rr] = s;
  }
  #pragma unroll
  for (int m = 1; m < 16; m <<= 1) {
    #pragma unroll
    for (int rr = 0; rr < 4; ++rr) pv[rr] += __shfl_xor(pv[rr], m);
  }
  if (b == 0) {
    #pragma unroll
    for (int rr = 0; rr < 4; ++rr) val[m0 + a * 4 + rr] = pv[rr] + eb2v;
  }
}

__global__ void loss_kernel(const float* __restrict__ val, const float* __restrict__ pos,
                            const float* __restrict__ neg, const float* __restrict__ tgt,
                            const float* __restrict__ pwp, double* acc)
{
  const float pw = pwp[0];
  double l = 0.0, pk = 0.0, nk = 0.0;
  for (int m = blockIdx.x * blockDim.x + threadIdx.x; m < MM; m += gridDim.x * blockDim.x) {
    float v = val[m], p = pos[m], n = neg[m], t = tgt[m];
    float lp = log1pf(expf(-fabsf(v)));
    float spn = fmaxf(-v, 0.f) + lp;
    float spp = fmaxf(v, 0.f) + lp;
    float contrib = pw * t * spn + (1.f - t) * spp;
    l += (double)((p + n) * contrib);
    if (v >= 0.f) pk += (double)p; else nk += (double)n;
  }
  for (int o = 32; o; o >>= 1) {
    l += __shfl_down(l, o); pk += __shfl_down(pk, o); nk += __shfl_down(nk, o);
  }
  __shared__ double s0[4], s1[4], s2[4];
  int wid = threadIdx.x >> 6, lane = threadIdx.x & 63;
  if (lane == 0) { s0[wid] = l; s1[wid] = pk; s2[wid] = nk; }
  __syncthreads();
  if (threadIdx.x == 0) {
    double ta = 0.0, tb = 0.0, tc = 0.0;
    for (int w = 0; w < 4; ++w) { ta += s0[w]; tb += s1[w]; tc += s2[w]; }
    atomicAdd(&acc[2], ta); atomicAdd(&acc[3], tb); atomicAdd(&acc[4], tc);
  }
}

__global__ void writeout(const double* __restrict__ acc, float* __restrict__ out) {
  if (threadIdx.x == 0) {
    out[0] = (float)acc[2];
    out[1] = (float)acc[3];
    out[2] = (float)acc[4];
  }
}

extern "C" void kernel_launch(void* const* d_in, const int* in_sizes, int n_in,
                              void* d_out, int out_size, void* d_ws, size_t ws_size,
                              hipStream_t stream)
{
  (void)in_sizes; (void)n_in; (void)out_size; (void)ws_size;
  const float* init_vecs = (const float*)d_in[0];
  const float* W1  = (const float*)d_in[1];
  const float* b1  = (const float*)d_in[2];
  const float* W2  = (const float*)d_in[3];
  const float* b2  = (const float*)d_in[4];
  const float* eW1 = (const float*)d_in[5];
  const float* eb1 = (const float*)d_in[6];
  const float* eW2 = (const float*)d_in[7];
  const float* eb2 = (const float*)d_in[8];
  const float* pos = (const float*)d_in[9];
  const float* neg = (const float*)d_in[10];
  const float* tgt = (const float*)d_in[11];
  const int* inds  = (const int*)d_in[12];
  const int* pars  = (const int*)d_in[13];
  const int* rules = (const int*)d_in[14];
  const int* mask  = (const int*)d_in[15];

  char* ws = (char*)d_ws;
  float*    vec  = (float*)(ws + OFF_VEC);
  float*    hbuf = (float*)(ws + OFF_H);
  float*    val  = (float*)(ws + OFF_VAL);
  unsigned* cnt  = (unsigned*)(ws + OFF_CNT);
  unsigned* flg  = (unsigned*)(ws + OFF_FLG);
  double*   acc  = (double*)(ws + OFF_ACC);
  float*    pw   = (float*)(ws + OFF_PW);

  zero_scratch<<<41, 256, 0, stream>>>(cnt);
  init_copy<<<256, 256, 0, stream>>>(init_vecs, vec);
  scan_kernel<<<256, 256, 0, stream>>>(W1, b1, W2, b2, inds, pars, rules,
                                       vec, hbuf, cnt, flg);
  reduce_pn<<<128, 256, 0, stream>>>(pos, neg, acc);
  pw_kernel<<<1, 1, 0, stream>>>(acc, pw);
  eval_kernel<<<1024, 256, 0, stream>>>(vec, mask, eW1, eb1, eW2, eb2, val);
  loss_kernel<<<128, 256, 0, stream>>>(val, pos, neg, tgt, pw, acc);
  writeout<<<1, 1, 0, stream>>>(acc, (float*)d_out);
}

// Round 6
// 4058.274 us; speedup vs baseline: 1.9320x; 1.9320x over previous
//
#include <hip/hip_runtime.h>
#include <math.h>

#define EMB   256
#define TWOE  512
#define NINIT 1024
#define NSTEP 512
#define NPS   256
#define TOTAL (NINIT + NSTEP * NPS)   // 132096
#define MM    65536
#define NNODE (NSTEP * NPS)           // 131072
#define NKEY  (513 * 8)               // 4104 (level in [0,512], 8 rules)
#define BTH   512                     // scan threads per block

// ---- workspace layout (bytes) ----
#define OFF_VEC   0ull
#define OFF_VAL   (OFF_VEC + (size_t)TOTAL * EMB * 4)   // vec: 135266304
#define OFF_CNT   (OFF_VAL + (size_t)MM * 4)            // barrier counters (4KB)
#define OFF_ACC   (OFF_CNT + 4096)
#define OFF_PW    (OFF_ACC + 64)
#define OFF_LVL   (OFF_PW + 192)                        // level per vec row
#define OFF_KCNT  (OFF_LVL + (size_t)TOTAL * 4)
#define OFF_KOFS  (OFF_KCNT + (size_t)NKEY * 4)
#define OFF_NL    (OFF_KOFS + (size_t)NKEY * 4)
#define OFF_BROWS (OFF_NL + 256)                        // bucketed node ids

// acc layout: [0]=sum(pos) [1]=sum(neg) [2]=loss [3]=posOK [4]=negOK

// ---- coherence-point (bypass L1/L2) ops ----
__device__ __forceinline__ void store_dev_u32(unsigned* p, unsigned v) {
  asm volatile("global_store_dword %0, %1, off sc0 sc1" :: "v"(p), "v"(v) : "memory");
}
__device__ __forceinline__ void store_dev_f64(float* p, float2 v) {
  asm volatile("global_store_dwordx2 %0, %1, off sc0 sc1" :: "v"(p), "v"(v) : "memory");
}
__device__ __forceinline__ unsigned load_dev_u32(const unsigned* p) {
  unsigned r;
  asm volatile("global_load_dword %0, %1, off sc0 sc1\n\ts_waitcnt vmcnt(0)"
               : "=v"(r) : "v"(p) : "memory");
  return r;
}
// L1-bypassing (agent-scope) int load: sees same-block global stores through L2
__device__ __forceinline__ int load_lvl(const int* p) {
  return __hip_atomic_load(p, __ATOMIC_RELAXED, __HIP_MEMORY_SCOPE_AGENT);
}

// full-grid barrier (256 blocks): drain sc0sc1 stores, epoch broadcast
__device__ __forceinline__ void gbar_full(unsigned* gc, unsigned* gep) {
  asm volatile("s_waitcnt vmcnt(0)" ::: "memory");
  __syncthreads();
  if (threadIdx.x == 0) {
    unsigned old = __hip_atomic_fetch_add(gc, 1u, __ATOMIC_RELAXED, __HIP_MEMORY_SCOPE_AGENT);
    unsigned tgt = old / 256u + 1u;
    if ((old & 255u) == 255u) store_dev_u32(gep, tgt);
    else while (load_dev_u32(gep) < tgt) __builtin_amdgcn_s_sleep(1);
  }
  __syncthreads();
}

__global__ void zero_scratch(unsigned* cnt, double* acc) {
  for (int i = threadIdx.x; i < 1024; i += 256) cnt[i] = 0u;
  if (threadIdx.x < 8) acc[threadIdx.x] = 0.0;
}

__global__ void init_copy(const float* __restrict__ src, float* __restrict__ dst) {
  int i = blockIdx.x * blockDim.x + threadIdx.x;
  reinterpret_cast<float4*>(dst)[i] = reinterpret_cast<const float4*>(src)[i];
}

// ---- prepass: levels + (level,rule) bucketing. ONE block, 1024 threads. ----
__global__ __launch_bounds__(1024)
void prepass(const int* __restrict__ inds, const int* __restrict__ pars,
             const int* __restrict__ rules,
             int* __restrict__ lvl, int* __restrict__ kcnt, int* __restrict__ kofs,
             int* __restrict__ brows, int* __restrict__ nlp)
{
  __shared__ int scnt[NKEY];
  __shared__ int sofs[NKEY];
  __shared__ int swmax[16];
  const int t = threadIdx.x;
  if (t < NINIT) lvl[t] = 0;
  __syncthreads();
  int lmax = 0;
  for (int s = 0; s < NSTEP; ++s) {
    if (t < NPS) {
      int i = s * NPS + t;
      int l1 = load_lvl(&lvl[pars[2 * i]]);
      int l2 = load_lvl(&lvl[pars[2 * i + 1]]);
      int lv = 1 + (l1 > l2 ? l1 : l2);
      lvl[inds[i]] = lv;
      if (lv > lmax) lmax = lv;
    }
    __syncthreads();   // orders global stores (compiler drains vmcnt) + visibility
  }
  for (int o = 32; o; o >>= 1) lmax = max(lmax, __shfl_down(lmax, o));
  if ((t & 63) == 0) swmax[t >> 6] = lmax;
  __syncthreads();
  if (t == 0) {
    int m = 0;
    for (int w = 0; w < 16; ++w) m = max(m, swmax[w]);
    nlp[0] = m;
  }
  // histogram over (level, rule)
  for (int k = t; k < NKEY; k += 1024) scnt[k] = 0;
  __syncthreads();
  for (int i = t; i < NNODE; i += 1024) {
    int key = load_lvl(&lvl[inds[i]]) * 8 + rules[i >> 8];
    atomicAdd(&scnt[key], 1);
  }
  __syncthreads();
  if (t == 0) {
    int run = 0;
    for (int k = 0; k < NKEY; ++k) {
      sofs[k] = run; kofs[k] = run; kcnt[k] = scnt[k]; run += scnt[k];
    }
  }
  __syncthreads();
  for (int i = t; i < NNODE; i += 1024) {
    int key = load_lvl(&lvl[inds[i]]) * 8 + rules[i >> 8];
    int pos = atomicAdd(&sofs[key], 1);
    brows[pos] = i;
  }
}

// ---- level-scheduled scan: 256 blocks x 512 threads ----
// Per tile: 8 nodes of one (level,rule) bucket; full 2-layer MLP block-local.
// Thread (rg=tid>>7, cg=tid&127) owns rows {2rg,2rg+1} x cols {2cg,2cg+1}.
__global__ __launch_bounds__(BTH, 1)
void scan_kernel(const float* __restrict__ W1, const float* __restrict__ b1,
                 const float* __restrict__ W2, const float* __restrict__ b2,
                 const int* __restrict__ inds, const int* __restrict__ pars,
                 float* __restrict__ vec,
                 const int* __restrict__ kcnt, const int* __restrict__ kofs,
                 const int* __restrict__ brows, const int* __restrict__ nlp,
                 unsigned* __restrict__ cnt)
{
  __shared__ float pL[8][TWOE];        // 16KB parents; reused as h[8][256] in phase2
  __shared__ float wL[2][32][EMB];     // 64KB W chunk double-buffer
  __shared__ int snode[8], sorow[8], spar[16];
  const int tid = threadIdx.x;
  const int bid = blockIdx.x;
  const int rg = tid >> 7;             // 0..3
  const int cg2 = (tid & 127) * 2;     // col base
  unsigned* gc  = cnt;
  unsigned* gep = cnt + 32;
  const int NL = nlp[0];

  for (int lv = 1; lv <= NL; ++lv) {
    int cum[9]; cum[0] = 0;
    int cnts[8], ofss[8];
    #pragma unroll
    for (int r = 0; r < 8; ++r) {
      int c = kcnt[lv * 8 + r];
      cnts[r] = c; ofss[r] = kofs[lv * 8 + r];
      cum[r + 1] = cum[r] + ((c + 7) >> 3);
    }
    int rr = 0;
    for (int g = bid; g < cum[8]; g += 256) {
      while (g >= cum[rr + 1]) ++rr;
      const int t0 = g - cum[rr];
      const int cnt_b = cnts[rr];
      const int ofs_b = ofss[rr];
      const int tbase = t0 * 8;
      const float* __restrict__ W1r = W1 + (size_t)rr * TWOE * EMB;
      const float* __restrict__ W2r = W2 + (size_t)rr * EMB * EMB;

      __syncthreads();   // (A) prev tile's LDS reads complete
      if (tid < 16) {
        int slot = tbase + (tid >> 1);
        int node = brows[ofs_b + (slot < cnt_b ? slot : cnt_b - 1)];
        if ((tid & 1) == 0) { snode[tid >> 1] = node; sorow[tid >> 1] = inds[node]; }
        spar[tid] = pars[2 * node + (tid & 1)];
      }
      // issue W1 chunk 0 loads early
      float4 st[4];
      {
        const float4* gsrc = (const float4*)W1r;
        #pragma unroll
        for (int i = 0; i < 4; ++i) st[i] = gsrc[i * BTH + tid];
      }
      __syncthreads();   // (B) spar visible
      // gather parents -> pL (8 rows x 512 floats), unpredicated
      #pragma unroll
      for (int u = 0; u < 2; ++u) {
        int idx = tid + u * BTH;          // 0..1023
        int row = idx >> 7, c4 = idx & 127;
        int par = spar[2 * row + (c4 >> 6)];
        float4 v = *((const float4*)(vec + (size_t)par * EMB) + (c4 & 63));
        *((float4*)&pL[row][0] + c4) = v;
      }
      {
        float4* wdst = (float4*)&wL[0][0][0];
        #pragma unroll
        for (int i = 0; i < 4; ++i) wdst[i * BTH + tid] = st[i];
      }
      __syncthreads();   // (C) pL + wL[0] ready

      float bA = b1[rr * EMB + cg2], bB = b1[rr * EMB + cg2 + 1];
      float acc[2][2];
      acc[0][0] = bA; acc[0][1] = bB; acc[1][0] = bA; acc[1][1] = bB;
      // phase 1: K=512 in 16 chunks of 32
      for (int c = 0; c < 16; ++c) {
        const float4* gnext = (c < 15) ? ((const float4*)W1r + (size_t)(c + 1) * 2048)
                                       : ((const float4*)W2r);   // prefetch W2 chunk 0
        #pragma unroll
        for (int i = 0; i < 4; ++i) st[i] = gnext[i * BTH + tid];
        const int kb = c * 32;
        const float (*wc)[EMB] = wL[c & 1];
        #pragma unroll
        for (int k4 = 0; k4 < 8; ++k4) {
          const int kg = kb + k4 * 4;
          float4 p0 = *(const float4*)&pL[rg * 2 + 0][kg];
          float4 p1 = *(const float4*)&pL[rg * 2 + 1][kg];
          #pragma unroll
          for (int kk = 0; kk < 4; ++kk) {
            float2 w = *(const float2*)&wc[k4 * 4 + kk][cg2];
            float a0 = ((const float*)&p0)[kk];
            float a1 = ((const float*)&p1)[kk];
            acc[0][0] = fmaf(a0, w.x, acc[0][0]);
            acc[0][1] = fmaf(a0, w.y, acc[0][1]);
            acc[1][0] = fmaf(a1, w.x, acc[1][0]);
            acc[1][1] = fmaf(a1, w.y, acc[1][1]);
          }
        }
        {
          float4* wdst = (float4*)&wL[(c + 1) & 1][0][0];
          #pragma unroll
          for (int i = 0; i < 4; ++i) wdst[i * BTH + tid] = st[i];
        }
        __syncthreads();
      }
      // relu + write h into pL region (rows stride TWOE, first 256 cols used)
      #pragma unroll
      for (int i = 0; i < 2; ++i) {
        float2 hv = make_float2(fmaxf(acc[i][0], 0.f), fmaxf(acc[i][1], 0.f));
        *(float2*)&pL[rg * 2 + i][cg2] = hv;
      }
      __syncthreads();   // (D) h ready
      float c2A = b2[rr * EMB + cg2], c2B = b2[rr * EMB + cg2 + 1];
      float acc2[2][2];
      acc2[0][0] = c2A; acc2[0][1] = c2B; acc2[1][0] = c2A; acc2[1][1] = c2B;
      // phase 2: K=256 in 8 chunks of 32 (wL[0] already holds chunk 0)
      for (int c = 0; c < 8; ++c) {
        if (c < 7) {
          const float4* gnext = (const float4*)W2r + (size_t)(c + 1) * 2048;
          #pragma unroll
          for (int i = 0; i < 4; ++i) st[i] = gnext[i * BTH + tid];
        }
        const int kb = c * 32;
        const float (*wc)[EMB] = wL[c & 1];
        #pragma unroll
        for (int k4 = 0; k4 < 8; ++k4) {
          const int kg = kb + k4 * 4;
          float4 p0 = *(const float4*)&pL[rg * 2 + 0][kg];
          float4 p1 = *(const float4*)&pL[rg * 2 + 1][kg];
          #pragma unroll
          for (int kk = 0; kk < 4; ++kk) {
            float2 w = *(const float2*)&wc[k4 * 4 + kk][cg2];
            float a0 = ((const float*)&p0)[kk];
            float a1 = ((const float*)&p1)[kk];
            acc2[0][0] = fmaf(a0, w.x, acc2[0][0]);
            acc2[0][1] = fmaf(a0, w.y, acc2[0][1]);
            acc2[1][0] = fmaf(a1, w.x, acc2[1][0]);
            acc2[1][1] = fmaf(a1, w.y, acc2[1][1]);
          }
        }
        if (c < 7) {
          float4* wdst = (float4*)&wL[(c + 1) & 1][0][0];
          #pragma unroll
          for (int i = 0; i < 4; ++i) wdst[i * BTH + tid] = st[i];
        }
        __syncthreads();
      }
      // coherent scatter (guarded for partial tiles)
      #pragma unroll
      for (int i = 0; i < 2; ++i) {
        if (tbase + rg * 2 + i < cnt_b) {
          int orow = sorow[rg * 2 + i];
          store_dev_f64(vec + (size_t)orow * EMB + cg2,
                        make_float2(acc2[i][0], acc2[i][1]));
        }
      }
    }
    gbar_full(gc, gep);
  }
}

__global__ void reduce_pn(const float* __restrict__ pos, const float* __restrict__ neg,
                          double* acc) {
  double sp = 0.0, sn = 0.0;
  for (int m = blockIdx.x * blockDim.x + threadIdx.x; m < MM; m += gridDim.x * blockDim.x) {
    sp += (double)pos[m]; sn += (double)neg[m];
  }
  for (int o = 32; o; o >>= 1) { sp += __shfl_down(sp, o); sn += __shfl_down(sn, o); }
  __shared__ double rp[4], rn[4];
  int wid = threadIdx.x >> 6, lane = threadIdx.x & 63;
  if (lane == 0) { rp[wid] = sp; rn[wid] = sn; }
  __syncthreads();
  if (threadIdx.x == 0) {
    double tp = 0.0, tn = 0.0;
    for (int w = 0; w < 4; ++w) { tp += rp[w]; tn += rn[w]; }
    atomicAdd(&acc[0], tp); atomicAdd(&acc[1], tn);
  }
}

__global__ void pw_kernel(const double* __restrict__ acc, float* __restrict__ pw) {
  pw[0] = (float)(acc[1] / fmax(acc[0], 1.0));
}

__global__ __launch_bounds__(256)
void eval_kernel(const float* __restrict__ vec, const int* __restrict__ mask,
                 const float* __restrict__ eW1, const float* __restrict__ eb1,
                 const float* __restrict__ eW2, const float* __restrict__ eb2,
                 float* __restrict__ val)
{
  __shared__ float xL[64][36];
  __shared__ float wLx[32][260];
  __shared__ int mrow[64];
  const int tid = threadIdx.x;
  const int a = tid >> 4, b = tid & 15;
  const int m0 = blockIdx.x * 64;
  if (tid < 64) mrow[tid] = mask[m0 + tid];
  __syncthreads();

  float acc[4][16];
  #pragma unroll
  for (int i = 0; i < 4; ++i)
    #pragma unroll
    for (int j = 0; j < 16; ++j) acc[i][j] = 0.f;

  for (int c = 0; c < 8; ++c) {
    const int e0 = c * 32;
    for (int idx = tid; idx < 64 * 8; idx += 256) {
      int rr = idx >> 3, e4 = idx & 7;
      float4 v = reinterpret_cast<const float4*>(vec + (size_t)mrow[rr] * EMB + e0)[e4];
      reinterpret_cast<float4*>(&xL[rr][0])[e4] = v;
    }
    for (int idx = tid; idx < 32 * 64; idx += 256) {
      int e = idx >> 6, k4 = idx & 63;
      reinterpret_cast<float4*>(&wLx[e][0])[k4] =
          reinterpret_cast<const float4*>(eW1 + (size_t)(e0 + e) * EMB)[k4];
    }
    __syncthreads();
    #pragma unroll 4
    for (int e = 0; e < 32; ++e) {
      float xs[4];
      #pragma unroll
      for (int rr = 0; rr < 4; ++rr) xs[rr] = xL[a * 4 + rr][e];
      const float4* wr = reinterpret_cast<const float4*>(&wLx[e][0]) + b * 4;
      float wk[16];
      *reinterpret_cast<float4*>(&wk[0])  = wr[0];
      *reinterpret_cast<float4*>(&wk[4])  = wr[1];
      *reinterpret_cast<float4*>(&wk[8])  = wr[2];
      *reinterpret_cast<float4*>(&wk[12]) = wr[3];
      #pragma unroll
      for (int rr = 0; rr < 4; ++rr)
        #pragma unroll
        for (int kk = 0; kk < 16; ++kk)
          acc[rr][kk] = fmaf(xs[rr], wk[kk], acc[rr][kk]);
    }
    __syncthreads();
  }

  float eb2v = eb2[0];
  float pv[4];
  #pragma unroll
  for (int rr = 0; rr < 4; ++rr) {
    float s = 0.f;
    #pragma unroll
    for (int kk = 0; kk < 16; ++kk) {
      float h = acc[rr][kk] + eb1[b * 16 + kk];
      h = fmaxf(h, 0.f);
      s += h * eW2[b * 16 + kk];
    }
    pv[rr] = s;
  }
  #pragma unroll
  for (int m = 1; m < 16; m <<= 1) {
    #pragma unroll
    for (int rr = 0; rr < 4; ++rr) pv[rr] += __shfl_xor(pv[rr], m);
  }
  if (b == 0) {
    #pragma unroll
    for (int rr = 0; rr < 4; ++rr) val[m0 + a * 4 + rr] = pv[rr] + eb2v;
  }
}

__global__ void loss_kernel(const float* __restrict__ val, const float* __restrict__ pos,
                            const float* __restrict__ neg, const float* __restrict__ tgt,
                            const float* __restrict__ pwp, double* acc)
{
  const float pw = pwp[0];
  double l = 0.0, pk = 0.0, nk = 0.0;
  for (int m = blockIdx.x * blockDim.x + threadIdx.x; m < MM; m += gridDim.x * blockDim.x) {
    float v = val[m], p = pos[m], n = neg[m], t = tgt[m];
    float lp = log1pf(expf(-fabsf(v)));
    float spn = fmaxf(-v, 0.f) + lp;
    float spp = fmaxf(v, 0.f) + lp;
    float contrib = pw * t * spn + (1.f - t) * spp;
    l += (double)((p + n) * contrib);
    if (v >= 0.f) pk += (double)p; else nk += (double)n;
  }
  for (int o = 32; o; o >>= 1) {
    l += __shfl_down(l, o); pk += __shfl_down(pk, o); nk += __shfl_down(nk, o);
  }
  __shared__ double s0[4], s1[4], s2[4];
  int wid = threadIdx.x >> 6, lane = threadIdx.x & 63;
  if (lane == 0) { s0[wid] = l; s1[wid] = pk; s2[wid] = nk; }
  __syncthreads();
  if (threadIdx.x == 0) {
    double ta = 0.0, tb = 0.0, tc = 0.0;
    for (int w = 0; w < 4; ++w) { ta += s0[w]; tb += s1[w]; tc += s2[w]; }
    atomicAdd(&acc[2], ta); atomicAdd(&acc[3], tb); atomicAdd(&acc[4], tc);
  }
}

__global__ void writeout(const double* __restrict__ acc, float* __restrict__ out) {
  if (threadIdx.x == 0) {
    out[0] = (float)acc[2];
    out[1] = (float)acc[3];
    out[2] = (float)acc[4];
  }
}

extern "C" void kernel_launch(void* const* d_in, const int* in_sizes, int n_in,
                              void* d_out, int out_size, void* d_ws, size_t ws_size,
                              hipStream_t stream)
{
  (void)in_sizes; (void)n_in; (void)out_size; (void)ws_size;
  const float* init_vecs = (const float*)d_in[0];
  const float* W1  = (const float*)d_in[1];
  const float* b1  = (const float*)d_in[2];
  const float* W2  = (const float*)d_in[3];
  const float* b2  = (const float*)d_in[4];
  const float* eW1 = (const float*)d_in[5];
  const float* eb1 = (const float*)d_in[6];
  const float* eW2 = (const float*)d_in[7];
  const float* eb2 = (const float*)d_in[8];
  const float* pos = (const float*)d_in[9];
  const float* neg = (const float*)d_in[10];
  const float* tgt = (const float*)d_in[11];
  const int* inds  = (const int*)d_in[12];
  const int* pars  = (const int*)d_in[13];
  const int* rules = (const int*)d_in[14];
  const int* mask  = (const int*)d_in[15];

  char* ws = (char*)d_ws;
  float*    vec   = (float*)(ws + OFF_VEC);
  float*    val   = (float*)(ws + OFF_VAL);
  unsigned* cnt   = (unsigned*)(ws + OFF_CNT);
  double*   acc   = (double*)(ws + OFF_ACC);
  float*    pw    = (float*)(ws + OFF_PW);
  int*      lvl   = (int*)(ws + OFF_LVL);
  int*      kcnt  = (int*)(ws + OFF_KCNT);
  int*      kofs  = (int*)(ws + OFF_KOFS);
  int*      nlp   = (int*)(ws + OFF_NL);
  int*      brows = (int*)(ws + OFF_BROWS);

  zero_scratch<<<1, 256, 0, stream>>>(cnt, acc);
  prepass<<<1, 1024, 0, stream>>>(inds, pars, rules, lvl, kcnt, kofs, brows, nlp);
  init_copy<<<256, 256, 0, stream>>>(init_vecs, vec);
  scan_kernel<<<256, BTH, 0, stream>>>(W1, b1, W2, b2, inds, pars, vec,
                                       kcnt, kofs, brows, nlp, cnt);
  reduce_pn<<<128, 256, 0, stream>>>(pos, neg, acc);
  pw_kernel<<<1, 1, 0, stream>>>(acc, pw);
  eval_kernel<<<1024, 256, 0, stream>>>(vec, mask, eW1, eb1, eW2, eb2, val);
  loss_kernel<<<128, 256, 0, stream>>>(val, pos, neg, tgt, pw, acc);
  writeout<<<1, 1, 0, stream>>>(acc, (float*)d_out);
}

// Round 7
// 2358.017 us; speedup vs baseline: 3.3250x; 1.7211x over previous
//
#include <hip/hip_runtime.h>
#include <math.h>

#define EMB   256
#define TWOE  512
#define NINIT 1024
#define NSTEP 512
#define NPS   256
#define TOTAL (NINIT + NSTEP * NPS)   // 132096
#define MM    65536
#define NNODE (NSTEP * NPS)           // 131072
#define NKEY  2048                    // 256 levels x 8 rules
#define BTH   512
#define TROWS 16                      // rows per tile

// ---- workspace layout (bytes) ----
#define OFF_VEC   0ull
#define OFF_VAL   (OFF_VEC + (size_t)TOTAL * EMB * 4)   // 135266304
#define OFF_CNT   (OFF_VAL + (size_t)MM * 4)
#define OFF_ACC   (OFF_CNT + 4096)
#define OFF_PW    (OFF_ACC + 64)
#define OFF_KCNT  (OFF_PW + 192)
#define OFF_KOFS  (OFF_KCNT + (size_t)NKEY * 4)
#define OFF_NL    (OFF_KOFS + (size_t)NKEY * 4)
#define OFF_BROWS (OFF_NL + 256)

// acc layout: [0]=sum(pos) [1]=sum(neg) [2]=loss [3]=posOK [4]=negOK

// ---- coherence-point (bypass L1/L2) ops ----
__device__ __forceinline__ void store_dev_f32(float* p, float v) {
  asm volatile("global_store_dword %0, %1, off sc0 sc1" :: "v"(p), "v"(v) : "memory");
}
__device__ __forceinline__ void store_dev_u32(unsigned* p, unsigned v) {
  asm volatile("global_store_dword %0, %1, off sc0 sc1" :: "v"(p), "v"(v) : "memory");
}
__device__ __forceinline__ unsigned load_dev_u32(const unsigned* p) {
  unsigned r;
  asm volatile("global_load_dword %0, %1, off sc0 sc1\n\ts_waitcnt vmcnt(0)"
               : "=v"(r) : "v"(p) : "memory");
  return r;
}

// full-grid barrier (256 blocks): drain sc0sc1 stores, epoch broadcast
__device__ __forceinline__ void gbar_full(unsigned* gc, unsigned* gep) {
  asm volatile("s_waitcnt vmcnt(0)" ::: "memory");
  __syncthreads();
  if (threadIdx.x == 0) {
    unsigned old = __hip_atomic_fetch_add(gc, 1u, __ATOMIC_RELAXED, __HIP_MEMORY_SCOPE_AGENT);
    unsigned tgt = old / 256u + 1u;
    if ((old & 255u) == 255u) store_dev_u32(gep, tgt);
    else while (load_dev_u32(gep) < tgt) __builtin_amdgcn_s_sleep(1);
  }
  __syncthreads();
}

__global__ void zero_scratch(unsigned* cnt, double* acc) {
  for (int i = threadIdx.x; i < 1024; i += 256) cnt[i] = 0u;
  if (threadIdx.x < 8) acc[threadIdx.x] = 0.0;
}

__global__ void init_copy(const float* __restrict__ src, float* __restrict__ dst) {
  int i = blockIdx.x * blockDim.x + threadIdx.x;
  reinterpret_cast<float4*>(dst)[i] = reinterpret_cast<const float4*>(src)[i];
}

// ---- prepass, all-LDS: levels (u8) + (level,rule) bucketing. 1 block x 1024 ----
__global__ __launch_bounds__(1024)
void prepass(const int* __restrict__ pars, const int* __restrict__ rules,
             int* __restrict__ kcnt, int* __restrict__ kofs,
             int* __restrict__ brows, int* __restrict__ nlp)
{
  __shared__ unsigned char slvl[TOTAL];   // 129KB
  __shared__ int scnt[NKEY];              // 8KB
  __shared__ int sofs[NKEY];              // 8KB
  __shared__ int swmax[16];
  const int t = threadIdx.x;
  for (int i = t; i < NINIT; i += 1024) slvl[i] = 0;
  for (int k = t; k < NKEY; k += 1024) scnt[k] = 0;
  __syncthreads();
  int lmax = 0;
  for (int s = 0; s < NSTEP; ++s) {
    if (t < NPS) {
      int i = s * NPS + t;
      int l1 = slvl[pars[2 * i]];
      int l2 = slvl[pars[2 * i + 1]];
      int lv = 1 + (l1 > l2 ? l1 : l2);
      slvl[NINIT + i] = (unsigned char)lv;   // write range disjoint from reads
      if (lv > lmax) lmax = lv;
    }
    __syncthreads();
  }
  for (int o = 32; o; o >>= 1) lmax = max(lmax, __shfl_down(lmax, o));
  if ((t & 63) == 0) swmax[t >> 6] = lmax;
  __syncthreads();
  if (t == 0) {
    int m = 0;
    for (int w = 0; w < 16; ++w) m = max(m, swmax[w]);
    nlp[0] = m;
  }
  // histogram
  for (int i = t; i < NNODE; i += 1024) {
    int key = (int)slvl[NINIT + i] * 8 + rules[i >> 8];
    atomicAdd(&scnt[key], 1);
  }
  __syncthreads();
  if (t == 0) {
    int run = 0;
    for (int k = 0; k < NKEY; ++k) {
      kofs[k] = run; sofs[k] = run; kcnt[k] = scnt[k]; run += scnt[k];
    }
  }
  __syncthreads();
  for (int i = t; i < NNODE; i += 1024) {
    int key = (int)slvl[NINIT + i] * 8 + rules[i >> 8];
    int pos = atomicAdd(&sofs[key], 1);
    brows[pos] = i;
  }
}

// ---- level-scheduled scan: 256 blocks x 512 threads, 16-row tiles ----
// thread: cols {x, x+128}, rows r0..r0+3 (x=tid&127, r0=(tid>>7)*4)
__global__ __launch_bounds__(BTH, 1)
void scan_kernel(const float* __restrict__ W1, const float* __restrict__ b1,
                 const float* __restrict__ W2, const float* __restrict__ b2,
                 const int* __restrict__ pars, float* __restrict__ vec,
                 const int* __restrict__ kcnt, const int* __restrict__ kofs,
                 const int* __restrict__ brows, const int* __restrict__ nlp,
                 unsigned* __restrict__ cnt)
{
  __shared__ float pL[TROWS][TWOE];     // 32KB parents; h reuses cols 0..255
  __shared__ float wL[2][32][EMB];      // 64KB W chunk double-buffer
  __shared__ int spar[2 * TROWS];
  __shared__ int sorow[TROWS];
  const int tid = threadIdx.x;
  const int bid = blockIdx.x;
  const int x = tid & 127;
  const int r0 = (tid >> 7) * 4;
  unsigned* gc  = cnt;
  unsigned* gep = cnt + 32;
  const int NL = nlp[0];
  const int xcd = bid & 7, jb = bid >> 3;

  for (int lv = 1; lv <= NL; ++lv) {
    int cum[9]; cum[0] = 0;
    int cnts[8], ofss[8];
    #pragma unroll
    for (int r = 0; r < 8; ++r) {
      int c = kcnt[lv * 8 + r];
      cnts[r] = c; ofss[r] = kofs[lv * 8 + r];
      cum[r + 1] = cum[r] + ((c + TROWS - 1) / TROWS);
    }
    const int G = cum[8];
    const int q = G >> 3, rm = G & 7;
    const int Gx = q + (xcd < rm ? 1 : 0);
    const int sx = xcd * q + (xcd < rm ? xcd : rm);   // bijective XCD swizzle
    for (int j = jb; j < Gx; j += 32) {
      const int g = sx + j;
      int rr = 0;
      while (g >= cum[rr + 1]) ++rr;
      const int t0 = g - cum[rr];
      const int cnt_b = cnts[rr], ofs_b = ofss[rr];
      const int tbase = t0 * TROWS;
      const float* __restrict__ W1r = W1 + (size_t)rr * TWOE * EMB;
      const float* __restrict__ W2r = W2 + (size_t)rr * EMB * EMB;

      __syncthreads();   // (A) prev tile LDS reads complete
      if (tid < 2 * TROWS) {
        int slot = tbase + (tid >> 1);
        if (slot >= cnt_b) slot = cnt_b - 1;
        int node = brows[ofs_b + slot];
        spar[tid] = pars[2 * node + (tid & 1)];
        if ((tid & 1) == 0) sorow[tid >> 1] = NINIT + node;
      }
      float4 st0, st1, st2, st3;
      {
        const float4* gsrc = (const float4*)W1r;
        st0 = gsrc[tid]; st1 = gsrc[BTH + tid];
        st2 = gsrc[2 * BTH + tid]; st3 = gsrc[3 * BTH + tid];
      }
      __syncthreads();   // (B) spar visible
      #pragma unroll
      for (int u = 0; u < 4; ++u) {
        int idx = tid + u * BTH;        // 0..2047: 16 rows x 128 float4
        int row = idx >> 7, c4 = idx & 127;
        int par = spar[2 * row + (c4 >> 6)];
        *((float4*)&pL[row][0] + c4) =
            *((const float4*)(vec + (size_t)par * EMB) + (c4 & 63));
      }
      {
        float4* wdst = (float4*)&wL[0][0][0];
        wdst[tid] = st0; wdst[BTH + tid] = st1;
        wdst[2 * BTH + tid] = st2; wdst[3 * BTH + tid] = st3;
      }
      __syncthreads();   // (C) pL + wL[0] ready

      float bA = b1[rr * EMB + x], bB = b1[rr * EMB + x + 128];
      float a00=bA,a01=bB, a10=bA,a11=bB, a20=bA,a21=bB, a30=bA,a31=bB;
      // phase 1: K=512, 16 chunks of 32
      for (int c = 0; c < 16; ++c) {
        const float4* gnext = (c < 15) ? ((const float4*)W1r + (size_t)(c + 1) * 2048)
                                       : ((const float4*)W2r);   // W2 chunk 0
        st0 = gnext[tid]; st1 = gnext[BTH + tid];
        st2 = gnext[2 * BTH + tid]; st3 = gnext[3 * BTH + tid];
        const int kb = c * 32;
        const float (*wc)[EMB] = wL[c & 1];
        #pragma unroll
        for (int k4 = 0; k4 < 8; ++k4) {
          const int kg = kb + k4 * 4;
          float4 p0 = *(const float4*)&pL[r0 + 0][kg];
          float4 p1 = *(const float4*)&pL[r0 + 1][kg];
          float4 p2 = *(const float4*)&pL[r0 + 2][kg];
          float4 p3 = *(const float4*)&pL[r0 + 3][kg];
          #pragma unroll
          for (int kk = 0; kk < 4; ++kk) {
            float w0 = wc[k4 * 4 + kk][x];
            float w1 = wc[k4 * 4 + kk][x + 128];
            float e0 = ((const float*)&p0)[kk], e1 = ((const float*)&p1)[kk];
            float e2 = ((const float*)&p2)[kk], e3 = ((const float*)&p3)[kk];
            a00 = fmaf(e0, w0, a00); a01 = fmaf(e0, w1, a01);
            a10 = fmaf(e1, w0, a10); a11 = fmaf(e1, w1, a11);
            a20 = fmaf(e2, w0, a20); a21 = fmaf(e2, w1, a21);
            a30 = fmaf(e3, w0, a30); a31 = fmaf(e3, w1, a31);
          }
        }
        {
          float4* wdst = (float4*)&wL[(c + 1) & 1][0][0];
          wdst[tid] = st0; wdst[BTH + tid] = st1;
          wdst[2 * BTH + tid] = st2; wdst[3 * BTH + tid] = st3;
        }
        __syncthreads();
      }
      // relu -> h in pL cols 0..255
      pL[r0 + 0][x] = fmaxf(a00, 0.f); pL[r0 + 0][x + 128] = fmaxf(a01, 0.f);
      pL[r0 + 1][x] = fmaxf(a10, 0.f); pL[r0 + 1][x + 128] = fmaxf(a11, 0.f);
      pL[r0 + 2][x] = fmaxf(a20, 0.f); pL[r0 + 2][x + 128] = fmaxf(a21, 0.f);
      pL[r0 + 3][x] = fmaxf(a30, 0.f); pL[r0 + 3][x + 128] = fmaxf(a31, 0.f);
      __syncthreads();   // (D) h ready
      float cA = b2[rr * EMB + x], cB = b2[rr * EMB + x + 128];
      float o00=cA,o01=cB, o10=cA,o11=cB, o20=cA,o21=cB, o30=cA,o31=cB;
      // phase 2: K=256, 8 chunks (wL[0] holds chunk 0 already)
      for (int c = 0; c < 8; ++c) {
        if (c < 7) {
          const float4* gnext = (const float4*)W2r + (size_t)(c + 1) * 2048;
          st0 = gnext[tid]; st1 = gnext[BTH + tid];
          st2 = gnext[2 * BTH + tid]; st3 = gnext[3 * BTH + tid];
        }
        const int kb = c * 32;
        const float (*wc)[EMB] = wL[c & 1];
        #pragma unroll
        for (int k4 = 0; k4 < 8; ++k4) {
          const int kg = kb + k4 * 4;
          float4 p0 = *(const float4*)&pL[r0 + 0][kg];
          float4 p1 = *(const float4*)&pL[r0 + 1][kg];
          float4 p2 = *(const float4*)&pL[r0 + 2][kg];
          float4 p3 = *(const float4*)&pL[r0 + 3][kg];
          #pragma unroll
          for (int kk = 0; kk < 4; ++kk) {
            float w0 = wc[k4 * 4 + kk][x];
            float w1 = wc[k4 * 4 + kk][x + 128];
            float e0 = ((const float*)&p0)[kk], e1 = ((const float*)&p1)[kk];
            float e2 = ((const float*)&p2)[kk], e3 = ((const float*)&p3)[kk];
            o00 = fmaf(e0, w0, o00); o01 = fmaf(e0, w1, o01);
            o10 = fmaf(e1, w0, o10); o11 = fmaf(e1, w1, o11);
            o20 = fmaf(e2, w0, o20); o21 = fmaf(e2, w1, o21);
            o30 = fmaf(e3, w0, o30); o31 = fmaf(e3, w1, o31);
          }
        }
        if (c < 7) {
          float4* wdst = (float4*)&wL[(c + 1) & 1][0][0];
          wdst[tid] = st0; wdst[BTH + tid] = st1;
          wdst[2 * BTH + tid] = st2; wdst[3 * BTH + tid] = st3;
          __syncthreads();
        }
      }
      // coherent scatter (guard partial tiles)
      float oa[4] = {o00, o10, o20, o30};
      float ob[4] = {o01, o11, o21, o31};
      #pragma unroll
      for (int i = 0; i < 4; ++i) {
        if (tbase + r0 + i < cnt_b) {
          float* vp = vec + (size_t)sorow[r0 + i] * EMB;
          store_dev_f32(vp + x, oa[i]);
          store_dev_f32(vp + x + 128, ob[i]);
        }
      }
    }
    gbar_full(gc, gep);
  }
}

__global__ void reduce_pn(const float* __restrict__ pos, const float* __restrict__ neg,
                          double* acc) {
  double sp = 0.0, sn = 0.0;
  for (int m = blockIdx.x * blockDim.x + threadIdx.x; m < MM; m += gridDim.x * blockDim.x) {
    sp += (double)pos[m]; sn += (double)neg[m];
  }
  for (int o = 32; o; o >>= 1) { sp += __shfl_down(sp, o); sn += __shfl_down(sn, o); }
  __shared__ double rp[4], rn[4];
  int wid = threadIdx.x >> 6, lane = threadIdx.x & 63;
  if (lane == 0) { rp[wid] = sp; rn[wid] = sn; }
  __syncthreads();
  if (threadIdx.x == 0) {
    double tp = 0.0, tn = 0.0;
    for (int w = 0; w < 4; ++w) { tp += rp[w]; tn += rn[w]; }
    atomicAdd(&acc[0], tp); atomicAdd(&acc[1], tn);
  }
}

__global__ void pw_kernel(const double* __restrict__ acc, float* __restrict__ pw) {
  pw[0] = (float)(acc[1] / fmax(acc[0], 1.0));
}

__global__ __launch_bounds__(256)
void eval_kernel(const float* __restrict__ vec, const int* __restrict__ mask,
                 const float* __restrict__ eW1, const float* __restrict__ eb1,
                 const float* __restrict__ eW2, const float* __restrict__ eb2,
                 float* __restrict__ val)
{
  __shared__ float xL[64][36];
  __shared__ float wLx[32][260];
  __shared__ int mrow[64];
  const int tid = threadIdx.x;
  const int a = tid >> 4, b = tid & 15;
  const int m0 = blockIdx.x * 64;
  if (tid < 64) mrow[tid] = mask[m0 + tid];
  __syncthreads();

  float acc[4][16];
  #pragma unroll
  for (int i = 0; i < 4; ++i)
    #pragma unroll
    for (int j = 0; j < 16; ++j) acc[i][j] = 0.f;

  for (int c = 0; c < 8; ++c) {
    const int e0 = c * 32;
    for (int idx = tid; idx < 64 * 8; idx += 256) {
      int rr = idx >> 3, e4 = idx & 7;
      float4 v = reinterpret_cast<const float4*>(vec + (size_t)mrow[rr] * EMB + e0)[e4];
      reinterpret_cast<float4*>(&xL[rr][0])[e4] = v;
    }
    for (int idx = tid; idx < 32 * 64; idx += 256) {
      int e = idx >> 6, k4 = idx & 63;
      reinterpret_cast<float4*>(&wLx[e][0])[k4] =
          reinterpret_cast<const float4*>(eW1 + (size_t)(e0 + e) * EMB)[k4];
    }
    __syncthreads();
    #pragma unroll 4
    for (int e = 0; e < 32; ++e) {
      float xs[4];
      #pragma unroll
      for (int rr = 0; rr < 4; ++rr) xs[rr] = xL[a * 4 + rr][e];
      const float4* wr = reinterpret_cast<const float4*>(&wLx[e][0]) + b * 4;
      float wk[16];
      *reinterpret_cast<float4*>(&wk[0])  = wr[0];
      *reinterpret_cast<float4*>(&wk[4])  = wr[1];
      *reinterpret_cast<float4*>(&wk[8])  = wr[2];
      *reinterpret_cast<float4*>(&wk[12]) = wr[3];
      #pragma unroll
      for (int rr = 0; rr < 4; ++rr)
        #pragma unroll
        for (int kk = 0; kk < 16; ++kk)
          acc[rr][kk] = fmaf(xs[rr], wk[kk], acc[rr][kk]);
    }
    __syncthreads();
  }

  float eb2v = eb2[0];
  float pv[4];
  #pragma unroll
  for (int rr = 0; rr < 4; ++rr) {
    float s = 0.f;
    #pragma unroll
    for (int kk = 0; kk < 16; ++kk) {
      float h = acc[rr][kk] + eb1[b * 16 + kk];
      h = fmaxf(h, 0.f);
      s += h * eW2[b * 16 + kk];
    }
    pv[rr] = s;
  }
  #pragma unroll
  for (int m = 1; m < 16; m <<= 1) {
    #pragma unroll
    for (int rr = 0; rr < 4; ++rr) pv[rr] += __shfl_xor(pv[rr], m);
  }
  if (b == 0) {
    #pragma unroll
    for (int rr = 0; rr < 4; ++rr) val[m0 + a * 4 + rr] = pv[rr] + eb2v;
  }
}

__global__ void loss_kernel(const float* __restrict__ val, const float* __restrict__ pos,
                            const float* __restrict__ neg, const float* __restrict__ tgt,
                            const float* __restrict__ pwp, double* acc)
{
  const float pw = pwp[0];
  double l = 0.0, pk = 0.0, nk = 0.0;
  for (int m = blockIdx.x * blockDim.x + threadIdx.x; m < MM; m += gridDim.x * blockDim.x) {
    float v = val[m], p = pos[m], n = neg[m], t = tgt[m];
    float lp = log1pf(expf(-fabsf(v)));
    float spn = fmaxf(-v, 0.f) + lp;
    float spp = fmaxf(v, 0.f) + lp;
    float contrib = pw * t * spn + (1.f - t) * spp;
    l += (double)((p + n) * contrib);
    if (v >= 0.f) pk += (double)p; else nk += (double)n;
  }
  for (int o = 32; o; o >>= 1) {
    l += __shfl_down(l, o); pk += __shfl_down(pk, o); nk += __shfl_down(nk, o);
  }
  __shared__ double s0[4], s1[4], s2[4];
  int wid = threadIdx.x >> 6, lane = threadIdx.x & 63;
  if (lane == 0) { s0[wid] = l; s1[wid] = pk; s2[wid] = nk; }
  __syncthreads();
  if (threadIdx.x == 0) {
    double ta = 0.0, tb = 0.0, tc = 0.0;
    for (int w = 0; w < 4; ++w) { ta += s0[w]; tb += s1[w]; tc += s2[w]; }
    atomicAdd(&acc[2], ta); atomicAdd(&acc[3], tb); atomicAdd(&acc[4], tc);
  }
}

__global__ void writeout(const double* __restrict__ acc, float* __restrict__ out) {
  if (threadIdx.x == 0) {
    out[0] = (float)acc[2];
    out[1] = (float)acc[3];
    out[2] = (float)acc[4];
  }
}

extern "C" void kernel_launch(void* const* d_in, const int* in_sizes, int n_in,
                              void* d_out, int out_size, void* d_ws, size_t ws_size,
                              hipStream_t stream)
{
  (void)in_sizes; (void)n_in; (void)out_size; (void)ws_size;
  const float* init_vecs = (const float*)d_in[0];
  const float* W1  = (const float*)d_in[1];
  const float* b1  = (const float*)d_in[2];
  const float* W2  = (const float*)d_in[3];
  const float* b2  = (const float*)d_in[4];
  const float* eW1 = (const float*)d_in[5];
  const float* eb1 = (const float*)d_in[6];
  const float* eW2 = (const float*)d_in[7];
  const float* eb2 = (const float*)d_in[8];
  const float* pos = (const float*)d_in[9];
  const float* neg = (const float*)d_in[10];
  const float* tgt = (const float*)d_in[11];
  const int* pars  = (const int*)d_in[13];
  const int* rules = (const int*)d_in[14];
  const int* mask  = (const int*)d_in[15];

  char* ws = (char*)d_ws;
  float*    vec   = (float*)(ws + OFF_VEC);
  float*    val   = (float*)(ws + OFF_VAL);
  unsigned* cnt   = (unsigned*)(ws + OFF_CNT);
  double*   acc   = (double*)(ws + OFF_ACC);
  float*    pw    = (float*)(ws + OFF_PW);
  int*      kcnt  = (int*)(ws + OFF_KCNT);
  int*      kofs  = (int*)(ws + OFF_KOFS);
  int*      nlp   = (int*)(ws + OFF_NL);
  int*      brows = (int*)(ws + OFF_BROWS);

  zero_scratch<<<1, 256, 0, stream>>>(cnt, acc);
  prepass<<<1, 1024, 0, stream>>>(pars, rules, kcnt, kofs, brows, nlp);
  init_copy<<<256, 256, 0, stream>>>(init_vecs, vec);
  scan_kernel<<<256, BTH, 0, stream>>>(W1, b1, W2, b2, pars, vec,
                                       kcnt, kofs, brows, nlp, cnt);
  reduce_pn<<<128, 256, 0, stream>>>(pos, neg, acc);
  pw_kernel<<<1, 1, 0, stream>>>(acc, pw);
  eval_kernel<<<1024, 256, 0, stream>>>(vec, mask, eW1, eb1, eW2, eb2, val);
  loss_kernel<<<128, 256, 0, stream>>>(val, pos, neg, tgt, pw, acc);
  writeout<<<1, 1, 0, stream>>>(acc, (float*)d_out);
}

// Round 9
// 1253.273 us; speedup vs baseline: 6.2560x; 1.8815x over previous
//
#include <hip/hip_runtime.h>
#include <math.h>

#define EMB   256
#define TWOE  512
#define NINIT 1024
#define NSTEP 512
#define NPS   256
#define TOTAL (NINIT + NSTEP * NPS)   // 132096
#define MM    65536
#define NNODE (NSTEP * NPS)           // 131072
#define NKEY  2048                    // 256 levels x 8 rules
#define BTH   512
#define TROWS 32                      // rows per tile

typedef short s16x8 __attribute__((ext_vector_type(8)));
typedef float f32x4 __attribute__((ext_vector_type(4)));

// ---- workspace layout (bytes) ----
#define OFF_VECH  0ull
#define OFF_VECL  ((size_t)TOTAL * EMB * 2)             // 67633152
#define OFF_VAL   (2ull * (size_t)TOTAL * EMB * 2)      // 135266304
#define OFF_CNT   (OFF_VAL + (size_t)MM * 4)
#define OFF_ACC   (OFF_CNT + 4096)
#define OFF_PW    (OFF_ACC + 64)
#define OFF_KCNT  (OFF_PW + 192)
#define OFF_KOFS  (OFF_KCNT + (size_t)NKEY * 4)
#define OFF_NL    (OFF_KOFS + (size_t)NKEY * 4)
#define OFF_BROWS (OFF_NL + 256)

// acc layout: [0]=sum(pos) [1]=sum(neg) [2]=loss [3]=posOK [4]=negOK

// ---- coherence-point (bypass L1/L2) ops ----
__device__ __forceinline__ void store_dev_u32(unsigned* p, unsigned v) {
  asm volatile("global_store_dword %0, %1, off sc0 sc1" :: "v"(p), "v"(v) : "memory");
}
__device__ __forceinline__ void store_dev_b64(void* p, uint2 v) {
  asm volatile("global_store_dwordx2 %0, %1, off sc0 sc1" :: "v"(p), "v"(v) : "memory");
}
__device__ __forceinline__ void store_dev_b128(void* p, uint4 v) {
  store_dev_b64(p, make_uint2(v.x, v.y));
  store_dev_b64((char*)p + 8, make_uint2(v.z, v.w));
}
__device__ __forceinline__ unsigned load_dev_u32(const unsigned* p) {
  unsigned r;
  asm volatile("global_load_dword %0, %1, off sc0 sc1\n\ts_waitcnt vmcnt(0)"
               : "=v"(r) : "v"(p) : "memory");
  return r;
}

// full-grid barrier (256 blocks)
__device__ __forceinline__ void gbar_full(unsigned* gc, unsigned* gep) {
  asm volatile("s_waitcnt vmcnt(0)" ::: "memory");
  __syncthreads();
  if (threadIdx.x == 0) {
    unsigned old = __hip_atomic_fetch_add(gc, 1u, __ATOMIC_RELAXED, __HIP_MEMORY_SCOPE_AGENT);
    unsigned tgt = old / 256u + 1u;
    if ((old & 255u) == 255u) store_dev_u32(gep, tgt);
    else while (load_dev_u32(gep) < tgt) __builtin_amdgcn_s_sleep(1);
  }
  __syncthreads();
}

// split 8 f32 -> packed bf16 hi (uint4) + lo (uint4), truncation split
__device__ __forceinline__ void split8(const float* f, uint4& h4, uint4& l4) {
  unsigned hu[8], lu[8];
  #pragma unroll
  for (int i = 0; i < 8; ++i) {
    unsigned u = __builtin_bit_cast(unsigned, f[i]);
    float rh = __builtin_bit_cast(float, u & 0xffff0000u);
    float rl = f[i] - rh;
    hu[i] = u >> 16;
    lu[i] = __builtin_bit_cast(unsigned, rl) >> 16;
  }
  h4 = make_uint4(hu[0] | (hu[1] << 16), hu[2] | (hu[3] << 16),
                  hu[4] | (hu[5] << 16), hu[6] | (hu[7] << 16));
  l4 = make_uint4(lu[0] | (lu[1] << 16), lu[2] | (lu[3] << 16),
                  lu[4] | (lu[5] << 16), lu[6] | (lu[7] << 16));
}

__global__ void zero_scratch(unsigned* cnt, double* acc) {
  for (int i = threadIdx.x; i < 1024; i += 256) cnt[i] = 0u;
  if (threadIdx.x < 8) acc[threadIdx.x] = 0.0;
}

// init rows fp32 -> bf16 hi/lo pair arrays
__global__ void init_convert(const float* __restrict__ src,
                             unsigned short* __restrict__ vh,
                             unsigned short* __restrict__ vl) {
  int slot = blockIdx.x * blockDim.x + threadIdx.x;   // 32768 slots x 8 elems
  float f[8];
  *(float4*)&f[0] = reinterpret_cast<const float4*>(src)[slot * 2];
  *(float4*)&f[4] = reinterpret_cast<const float4*>(src)[slot * 2 + 1];
  uint4 h4, l4;
  split8(f, h4, l4);
  *(uint4*)(vh + (size_t)slot * 8) = h4;
  *(uint4*)(vl + (size_t)slot * 8) = l4;
}

// ---- prepass, all-LDS: levels (u8) + (level,rule) bucketing. 1 block x 1024 ----
__global__ __launch_bounds__(1024)
void prepass(const int* __restrict__ pars, const int* __restrict__ rules,
             int* __restrict__ kcnt, int* __restrict__ kofs,
             int* __restrict__ brows, int* __restrict__ nlp)
{
  __shared__ unsigned char slvl[TOTAL];
  __shared__ int scnt[NKEY];
  __shared__ int sofs[NKEY];
  __shared__ int swmax[16];
  const int t = threadIdx.x;
  for (int i = t; i < NINIT; i += 1024) slvl[i] = 0;
  for (int k = t; k < NKEY; k += 1024) scnt[k] = 0;
  __syncthreads();
  int lmax = 0;
  for (int s = 0; s < NSTEP; ++s) {
    if (t < NPS) {
      int i = s * NPS + t;
      int l1 = slvl[pars[2 * i]];
      int l2 = slvl[pars[2 * i + 1]];
      int lv = 1 + (l1 > l2 ? l1 : l2);
      slvl[NINIT + i] = (unsigned char)lv;
      if (lv > lmax) lmax = lv;
    }
    __syncthreads();
  }
  for (int o = 32; o; o >>= 1) lmax = max(lmax, __shfl_down(lmax, o));
  if ((t & 63) == 0) swmax[t >> 6] = lmax;
  __syncthreads();
  if (t == 0) {
    int m = 0;
    for (int w = 0; w < 16; ++w) m = max(m, swmax[w]);
    nlp[0] = m;
  }
  for (int i = t; i < NNODE; i += 1024) {
    int key = (int)slvl[NINIT + i] * 8 + rules[i >> 8];
    atomicAdd(&scnt[key], 1);
  }
  __syncthreads();
  if (t == 0) {
    int run = 0;
    for (int k = 0; k < NKEY; ++k) {
      kofs[k] = run; sofs[k] = run; kcnt[k] = scnt[k]; run += scnt[k];
    }
  }
  __syncthreads();
  for (int i = t; i < NNODE; i += 1024) {
    int key = (int)slvl[NINIT + i] * 8 + rules[i >> 8];
    int pos = atomicAdd(&sofs[key], 1);
    brows[pos] = i;
  }
}

// ---- level-scheduled scan, split-bf16 MFMA: 256 blocks x 512 threads ----
// Tile: 32 rows x 256 cols. 8 waves: rw=w&1 (16-row half), cw=w>>1 (64-col strip).
// Per wave: 4 accumulator tiles (16x16), K via 3-term split-bf16 mfma.
__global__ __launch_bounds__(BTH, 1)
void scan_kernel(const float* __restrict__ W1, const float* __restrict__ b1,
                 const float* __restrict__ W2, const float* __restrict__ b2,
                 const int* __restrict__ pars,
                 unsigned short* __restrict__ vech, unsigned short* __restrict__ vecl,
                 const int* __restrict__ kcnt, const int* __restrict__ kofs,
                 const int* __restrict__ brows, const int* __restrict__ nlp,
                 unsigned* __restrict__ cnt)
{
  __shared__ short sW[2][2][8192];   // [buf][hi/lo][(g*64+lane)*8+i]  64KB
  __shared__ float hL[TROWS][260];   // h / out exchange, padded        33KB
  __shared__ int spar[2 * TROWS];
  __shared__ int sorow[TROWS];
  const int tid = threadIdx.x;
  const int bid = blockIdx.x;
  const int lane = tid & 63;
  const int w = tid >> 6;
  const int rw = w & 1, cw = w >> 1;
  const int row16 = lane & 15, kb8 = (lane >> 4) << 3;
  const int arow = (rw << 4) + row16;       // tile row this lane's A covers
  unsigned* gc  = cnt;
  unsigned* gep = cnt + 32;
  const int NL = nlp[0];
  const int xcd = bid & 7, jb = bid >> 3;

  // staging slot assignment: q = g*64 + l ; thread handles q=tid and q=tid+512
  const int g0 = tid >> 6, l0 = tid & 63;
  const int g1 = g0 + 8,   l1 = l0;

  for (int lv = 1; lv <= NL; ++lv) {
    int cum[9]; cum[0] = 0;
    int cnts[8], ofss[8];
    #pragma unroll
    for (int r = 0; r < 8; ++r) {
      int c = kcnt[lv * 8 + r];
      cnts[r] = c; ofss[r] = kofs[lv * 8 + r];
      cum[r + 1] = cum[r] + ((c + TROWS - 1) >> 5);
    }
    const int G = cum[8];
    const int q = G >> 3, rm = G & 7;
    const int Gx = q + (xcd < rm ? 1 : 0);
    const int sx = xcd * q + (xcd < rm ? xcd : rm);
    for (int j = jb; j < Gx; j += 32) {
      const int g = sx + j;
      int rr = 0;
      while (g >= cum[rr + 1]) ++rr;
      const int t0 = g - cum[rr];
      const int cnt_b = cnts[rr], ofs_b = ofss[rr];
      const int tbase = t0 * TROWS;
      const float* __restrict__ W1r = W1 + (size_t)rr * TWOE * EMB;
      const float* __restrict__ W2r = W2 + (size_t)rr * EMB * EMB;

      __syncthreads();   // (A) prev tile's LDS use complete
      if (tid < 2 * TROWS) {
        int slot = tbase + (tid >> 1);
        if (slot >= cnt_b) slot = cnt_b - 1;
        int node = brows[ofs_b + slot];
        spar[tid] = pars[2 * node + (tid & 1)];
        if ((tid & 1) == 0) sorow[tid >> 1] = NINIT + node;
      }
      // stage W1 chunk 0 (load fp32 -> split -> frag layout in LDS)
      float f[16];
      {
        const float* p0 = W1r + (size_t)((l0 >> 4) << 3) * EMB + (g0 << 4) + (l0 & 15);
        const float* p1 = W1r + (size_t)((l1 >> 4) << 3) * EMB + (g1 << 4) + (l1 & 15);
        #pragma unroll
        for (int i = 0; i < 8; ++i) { f[i] = p0[i * EMB]; f[8 + i] = p1[i * EMB]; }
        uint4 h4, l4;
        split8(f, h4, l4);
        *(uint4*)&sW[0][0][tid * 8] = h4;
        *(uint4*)&sW[0][1][tid * 8] = l4;
        split8(f + 8, h4, l4);
        *(uint4*)&sW[0][0][(tid + 512) * 8] = h4;
        *(uint4*)&sW[0][1][(tid + 512) * 8] = l4;
      }
      __syncthreads();   // (B) spar + sW[0] ready
      const int par0 = spar[2 * arow], par1 = spar[2 * arow + 1];
      float b1v[4];
      #pragma unroll
      for (int g4 = 0; g4 < 4; ++g4)
        b1v[g4] = b1[rr * EMB + (cw << 6) + (g4 << 4) + row16];

      // A chunk 0
      uint4 ahA, alA;
      {
        size_t off = (size_t)par0 * EMB + kb8;
        ahA = *(const uint4*)(vech + off);
        alA = *(const uint4*)(vecl + off);
      }
      f32x4 acc[4] = {{0,0,0,0},{0,0,0,0},{0,0,0,0},{0,0,0,0}};
      int curb = 0;
      // ---- phase 1: K=512 in 16 chunks of 32 ----
      for (int c = 0; c < 16; ++c) {
        // prefetch next W source (c==15 -> W2 chunk 0)
        const float* nsrc = (c < 15) ? W1r : W2r;
        const int nkb = (c < 15) ? (c + 1) * 32 : 0;
        {
          const float* p0 = nsrc + (size_t)(nkb + ((l0 >> 4) << 3)) * EMB + (g0 << 4) + (l0 & 15);
          const float* p1 = nsrc + (size_t)(nkb + ((l1 >> 4) << 3)) * EMB + (g1 << 4) + (l1 & 15);
          #pragma unroll
          for (int i = 0; i < 8; ++i) { f[i] = p0[i * EMB]; f[8 + i] = p1[i * EMB]; }
        }
        // prefetch next A
        uint4 ahB = ahA, alB = alA;
        if (c < 15) {
          int kglob = (c + 1) * 32 + kb8;
          int par = (kglob >> 8) ? par1 : par0;
          size_t off = (size_t)par * EMB + (kglob & 255);
          ahB = *(const uint4*)(vech + off);
          alB = *(const uint4*)(vecl + off);
        }
        // MFMA on current
        {
          s16x8 Ah = __builtin_bit_cast(s16x8, ahA);
          s16x8 Al = __builtin_bit_cast(s16x8, alA);
          const s16x8* bph = (const s16x8*)&sW[curb][0][0];
          const s16x8* bpl = (const s16x8*)&sW[curb][1][0];
          #pragma unroll
          for (int g4 = 0; g4 < 4; ++g4) {
            int gi = ((cw << 2) + g4) * 64 + lane;
            s16x8 Bh = bph[gi], Bl = bpl[gi];
            acc[g4] = __builtin_amdgcn_mfma_f32_16x16x32_bf16(Ah, Bh, acc[g4], 0, 0, 0);
            acc[g4] = __builtin_amdgcn_mfma_f32_16x16x32_bf16(Ah, Bl, acc[g4], 0, 0, 0);
            acc[g4] = __builtin_amdgcn_mfma_f32_16x16x32_bf16(Al, Bh, acc[g4], 0, 0, 0);
          }
        }
        // write next W chunk into other buffer
        {
          uint4 h4, l4;
          split8(f, h4, l4);
          *(uint4*)&sW[curb ^ 1][0][tid * 8] = h4;
          *(uint4*)&sW[curb ^ 1][1][tid * 8] = l4;
          split8(f + 8, h4, l4);
          *(uint4*)&sW[curb ^ 1][0][(tid + 512) * 8] = h4;
          *(uint4*)&sW[curb ^ 1][1][(tid + 512) * 8] = l4;
        }
        __syncthreads();
        curb ^= 1;
        ahA = ahB; alA = alB;
      }
      // h = relu(acc + b1) -> hL
      #pragma unroll
      for (int g4 = 0; g4 < 4; ++g4) {
        #pragma unroll
        for (int jj = 0; jj < 4; ++jj)
          hL[(rw << 4) + ((lane >> 4) << 2) + jj][(cw << 6) + (g4 << 4) + row16] =
              fmaxf(acc[g4][jj] + b1v[g4], 0.f);
      }
      __syncthreads();   // (D) h ready; sW[curb] holds W2 chunk 0
      float b2v[4];
      #pragma unroll
      for (int g4 = 0; g4 < 4; ++g4)
        b2v[g4] = b2[rr * EMB + (cw << 6) + (g4 << 4) + row16];
      f32x4 acc2[4] = {{0,0,0,0},{0,0,0,0},{0,0,0,0},{0,0,0,0}};
      // ---- phase 2: K=256 in 8 chunks ----
      for (int c2 = 0; c2 < 8; ++c2) {
        if (c2 < 7) {
          const int nkb = (c2 + 1) * 32;
          const float* p0 = W2r + (size_t)(nkb + ((l0 >> 4) << 3)) * EMB + (g0 << 4) + (l0 & 15);
          const float* p1 = W2r + (size_t)(nkb + ((l1 >> 4) << 3)) * EMB + (g1 << 4) + (l1 & 15);
          #pragma unroll
          for (int i = 0; i < 8; ++i) { f[i] = p0[i * EMB]; f[8 + i] = p1[i * EMB]; }
        }
        // A2 from hL
        uint4 a2h4, a2l4;
        {
          int kb = c2 * 32 + kb8;
          float af[8];
          *(float4*)&af[0] = *(const float4*)&hL[arow][kb];
          *(float4*)&af[4] = *(const float4*)&hL[arow][kb + 4];
          split8(af, a2h4, a2l4);
        }
        {
          s16x8 Ah = __builtin_bit_cast(s16x8, a2h4);
          s16x8 Al = __builtin_bit_cast(s16x8, a2l4);
          const s16x8* bph = (const s16x8*)&sW[curb][0][0];
          const s16x8* bpl = (const s16x8*)&sW[curb][1][0];
          #pragma unroll
          for (int g4 = 0; g4 < 4; ++g4) {
            int gi = ((cw << 2) + g4) * 64 + lane;
            s16x8 Bh = bph[gi], Bl = bpl[gi];
            acc2[g4] = __builtin_amdgcn_mfma_f32_16x16x32_bf16(Ah, Bh, acc2[g4], 0, 0, 0);
            acc2[g4] = __builtin_amdgcn_mfma_f32_16x16x32_bf16(Ah, Bl, acc2[g4], 0, 0, 0);
            acc2[g4] = __builtin_amdgcn_mfma_f32_16x16x32_bf16(Al, Bh, acc2[g4], 0, 0, 0);
          }
        }
        if (c2 < 7) {
          uint4 h4, l4;
          split8(f, h4, l4);
          *(uint4*)&sW[curb ^ 1][0][tid * 8] = h4;
          *(uint4*)&sW[curb ^ 1][1][tid * 8] = l4;
          split8(f + 8, h4, l4);
          *(uint4*)&sW[curb ^ 1][0][(tid + 512) * 8] = h4;
          *(uint4*)&sW[curb ^ 1][1][(tid + 512) * 8] = l4;
          __syncthreads();
          curb ^= 1;
        }
      }
      __syncthreads();   // all hL (A2) reads done
      // out -> hL
      #pragma unroll
      for (int g4 = 0; g4 < 4; ++g4) {
        #pragma unroll
        for (int jj = 0; jj < 4; ++jj)
          hL[(rw << 4) + ((lane >> 4) << 2) + jj][(cw << 6) + (g4 << 4) + row16] =
              acc2[g4][jj] + b2v[g4];
      }
      __syncthreads();
      // coalesced split store to vec hi/lo (coherent), guarded for partial tiles
      #pragma unroll
      for (int u = 0; u < 2; ++u) {
        int s = tid + u * 512;             // 1024 slots: 32 rows x 32 col-groups
        int row = s >> 5, c8 = (s & 31) * 8;
        float of[8];
        *(float4*)&of[0] = *(const float4*)&hL[row][c8];
        *(float4*)&of[4] = *(const float4*)&hL[row][c8 + 4];
        uint4 h4, l4;
        split8(of, h4, l4);
        if (tbase + row < cnt_b) {
          size_t off = (size_t)sorow[row] * EMB + c8;
          store_dev_b128(vech + off, h4);
          store_dev_b128(vecl + off, l4);
        }
      }
    }
    gbar_full(gc, gep);
  }
}

__global__ void reduce_pn(const float* __restrict__ pos, const float* __restrict__ neg,
                          double* acc) {
  double sp = 0.0, sn = 0.0;
  for (int m = blockIdx.x * blockDim.x + threadIdx.x; m < MM; m += gridDim.x * blockDim.x) {
    sp += (double)pos[m]; sn += (double)neg[m];
  }
  for (int o = 32; o; o >>= 1) { sp += __shfl_down(sp, o); sn += __shfl_down(sn, o); }
  __shared__ double rp[4], rn[4];
  int wid = threadIdx.x >> 6, lane = threadIdx.x & 63;
  if (lane == 0) { rp[wid] = sp; rn[wid] = sn; }
  __syncthreads();
  if (threadIdx.x == 0) {
    double tp = 0.0, tn = 0.0;
    for (int w = 0; w < 4; ++w) { tp += rp[w]; tn += rn[w]; }
    atomicAdd(&acc[0], tp); atomicAdd(&acc[1], tn);
  }
}

__global__ void pw_kernel(const double* __restrict__ acc, float* __restrict__ pw) {
  pw[0] = (float)(acc[1] / fmax(acc[0], 1.0));
}

__global__ __launch_bounds__(256)
void eval_kernel(const unsigned short* __restrict__ vh, const unsigned short* __restrict__ vl,
                 const int* __restrict__ mask,
                 const float* __restrict__ eW1, const float* __restrict__ eb1,
                 const float* __restrict__ eW2, const float* __restrict__ eb2,
                 float* __restrict__ val)
{
  __shared__ float xL[64][36];
  __shared__ float wLx[32][260];
  __shared__ int mrow[64];
  const int tid = threadIdx.x;
  const int a = tid >> 4, b = tid & 15;
  const int m0 = blockIdx.x * 64;
  if (tid < 64) mrow[tid] = mask[m0 + tid];
  __syncthreads();

  float acc[4][16];
  #pragma unroll
  for (int i = 0; i < 4; ++i)
    #pragma unroll
    for (int j = 0; j < 16; ++j) acc[i][j] = 0.f;

  for (int c = 0; c < 8; ++c) {
    const int e0 = c * 32;
    for (int idx = tid; idx < 64 * 4; idx += 256) {
      int rr = idx >> 2, u = idx & 3;
      size_t off = (size_t)mrow[rr] * EMB + e0 + u * 8;
      uint4 hv = *(const uint4*)(vh + off);
      uint4 lv = *(const uint4*)(vl + off);
      const unsigned* hu = (const unsigned*)&hv;
      const unsigned* lu = (const unsigned*)&lv;
      float fo[8];
      #pragma unroll
      for (int jj = 0; jj < 4; ++jj) {
        fo[2 * jj] = __builtin_bit_cast(float, (hu[jj] & 0xffffu) << 16) +
                     __builtin_bit_cast(float, (lu[jj] & 0xffffu) << 16);
        fo[2 * jj + 1] = __builtin_bit_cast(float, hu[jj] & 0xffff0000u) +
                         __builtin_bit_cast(float, lu[jj] & 0xffff0000u);
      }
      *(float4*)&xL[rr][u * 8] = *(float4*)&fo[0];
      *(float4*)&xL[rr][u * 8 + 4] = *(float4*)&fo[4];
    }
    for (int idx = tid; idx < 32 * 64; idx += 256) {
      int e = idx >> 6, k4 = idx & 63;
      reinterpret_cast<float4*>(&wLx[e][0])[k4] =
          reinterpret_cast<const float4*>(eW1 + (size_t)(e0 + e) * EMB)[k4];
    }
    __syncthreads();
    #pragma unroll 4
    for (int e = 0; e < 32; ++e) {
      float xs[4];
      #pragma unroll
      for (int rr = 0; rr < 4; ++rr) xs[rr] = xL[a * 4 + rr][e];
      const float4* wr = reinterpret_cast<const float4*>(&wLx[e][0]) + b * 4;
      float wk[16];
      *reinterpret_cast<float4*>(&wk[0])  = wr[0];
      *reinterpret_cast<float4*>(&wk[4])  = wr[1];
      *reinterpret_cast<float4*>(&wk[8])  = wr[2];
      *reinterpret_cast<float4*>(&wk[12]) = wr[3];
      #pragma unroll
      for (int rr = 0; rr < 4; ++rr)
        #pragma unroll
        for (int kk = 0; kk < 16; ++kk)
          acc[rr][kk] = fmaf(xs[rr], wk[kk], acc[rr][kk]);
    }
    __syncthreads();
  }

  float eb2v = eb2[0];
  float pv[4];
  #pragma unroll
  for (int rr = 0; rr < 4; ++rr) {
    float s = 0.f;
    #pragma unroll
    for (int kk = 0; kk < 16; ++kk) {
      float h = acc[rr][kk] + eb1[b * 16 + kk];
      h = fmaxf(h, 0.f);
      s += h * eW2[b * 16 + kk];
    }
    pv[rr] = s;
  }
  #pragma unroll
  for (int m = 1; m < 16; m <<= 1) {
    #pragma unroll
    for (int rr = 0; rr < 4; ++rr) pv[rr] += __shfl_xor(pv[rr], m);
  }
  if (b == 0) {
    #pragma unroll
    for (int rr = 0; rr < 4; ++rr) val[m0 + a * 4 + rr] = pv[rr] + eb2v;
  }
}

__global__ void loss_kernel(const float* __restrict__ val, const float* __restrict__ pos,
                            const float* __restrict__ neg, const float* __restrict__ tgt,
                            const float* __restrict__ pwp, double* acc)
{
  const float pw = pwp[0];
  double l = 0.0, pk = 0.0, nk = 0.0;
  for (int m = blockIdx.x * blockDim.x + threadIdx.x; m < MM; m += gridDim.x * blockDim.x) {
    float v = val[m], p = pos[m], n = neg[m], t = tgt[m];
    float lp = log1pf(expf(-fabsf(v)));
    float spn = fmaxf(-v, 0.f) + lp;
    float spp = fmaxf(v, 0.f) + lp;
    float contrib = pw * t * spn + (1.f - t) * spp;
    l += (double)((p + n) * contrib);
    if (v >= 0.f) pk += (double)p; else nk += (double)n;
  }
  for (int o = 32; o; o >>= 1) {
    l += __shfl_down(l, o); pk += __shfl_down(pk, o); nk += __shfl_down(nk, o);
  }
  __shared__ double s0[4], s1[4], s2[4];
  int wid = threadIdx.x >> 6, lane = threadIdx.x & 63;
  if (lane == 0) { s0[wid] = l; s1[wid] = pk; s2[wid] = nk; }
  __syncthreads();
  if (threadIdx.x == 0) {
    double ta = 0.0, tb = 0.0, tc = 0.0;
    for (int w = 0; w < 4; ++w) { ta += s0[w]; tb += s1[w]; tc += s2[w]; }
    atomicAdd(&acc[2], ta); atomicAdd(&acc[3], tb); atomicAdd(&acc[4], tc);
  }
}

__global__ void writeout(const double* __restrict__ acc, float* __restrict__ out) {
  if (threadIdx.x == 0) {
    out[0] = (float)acc[2];
    out[1] = (float)acc[3];
    out[2] = (float)acc[4];
  }
}

extern "C" void kernel_launch(void* const* d_in, const int* in_sizes, int n_in,
                              void* d_out, int out_size, void* d_ws, size_t ws_size,
                              hipStream_t stream)
{
  (void)in_sizes; (void)n_in; (void)out_size; (void)ws_size;
  const float* init_vecs = (const float*)d_in[0];
  const float* W1  = (const float*)d_in[1];
  const float* b1  = (const float*)d_in[2];
  const float* W2  = (const float*)d_in[3];
  const float* b2  = (const float*)d_in[4];
  const float* eW1 = (const float*)d_in[5];
  const float* eb1 = (const float*)d_in[6];
  const float* eW2 = (const float*)d_in[7];
  const float* eb2 = (const float*)d_in[8];
  const float* pos = (const float*)d_in[9];
  const float* neg = (const float*)d_in[10];
  const float* tgt = (const float*)d_in[11];
  const int* pars  = (const int*)d_in[13];
  const int* rules = (const int*)d_in[14];
  const int* mask  = (const int*)d_in[15];

  char* ws = (char*)d_ws;
  unsigned short* vech = (unsigned short*)(ws + OFF_VECH);
  unsigned short* vecl = (unsigned short*)(ws + OFF_VECL);
  float*    val   = (float*)(ws + OFF_VAL);
  unsigned* cnt   = (unsigned*)(ws + OFF_CNT);
  double*   acc   = (double*)(ws + OFF_ACC);
  float*    pw    = (float*)(ws + OFF_PW);
  int*      kcnt  = (int*)(ws + OFF_KCNT);
  int*      kofs  = (int*)(ws + OFF_KOFS);
  int*      nlp   = (int*)(ws + OFF_NL);
  int*      brows = (int*)(ws + OFF_BROWS);

  zero_scratch<<<1, 256, 0, stream>>>(cnt, acc);
  prepass<<<1, 1024, 0, stream>>>(pars, rules, kcnt, kofs, brows, nlp);
  init_convert<<<128, 256, 0, stream>>>(init_vecs, vech, vecl);
  scan_kernel<<<256, BTH, 0, stream>>>(W1, b1, W2, b2, pars, vech, vecl,
                                       kcnt, kofs, brows, nlp, cnt);
  reduce_pn<<<128, 256, 0, stream>>>(pos, neg, acc);
  pw_kernel<<<1, 1, 0, stream>>>(acc, pw);
  eval_kernel<<<1024, 256, 0, stream>>>(vech, vecl, mask, eW1, eb1, eW2, eb2, val);
  loss_kernel<<<128, 256, 0, stream>>>(val, pos, neg, tgt, pw, acc);
  writeout<<<1, 1, 0, stream>>>(acc, (float*)d_out);
}